// Round 5
// baseline (82.928 us; speedup 1.0000x reference)
//
#include <hip/hip_runtime.h>
#include <hip/hip_cooperative_groups.h>
#include <cstdint>

namespace cg = cooperative_groups;

#define HD __device__ __forceinline__

constexpr int B = 4, N = 8192, H = 128, W = 128, K = 8;
constexpr float BIGF = 1e10f;
constexpr int TOTPIX = B * H * W;   // 65536
constexpr int CAPP = 32;            // per-pixel list capacity (E[hits]~2.6)
constexpr int NBLK = 256;           // 1 block/CU -> co-residency guaranteed
constexpr int NTHR = 256;

HD bool keyless(float z1, int i1, float z2, int i2) {
    return (z1 < z2) || ((z1 == z2) && (i1 < i2));
}

// branchless unrolled insert into ascending (z,idx)-sorted top-K registers.
// Caller guarantees keyless(nz,ni, zk[K-1],ik[K-1]).
HD void insert_topk(float nz, int ni, float nd,
                    float (&zk)[K], int (&ik)[K], float (&dk)[K]) {
    bool lt[K];
#pragma unroll
    for (int j = 0; j < K; ++j) lt[j] = keyless(nz, ni, zk[j], ik[j]);
#pragma unroll
    for (int j = K - 1; j >= 1; --j) {
        if (lt[j]) {
            if (lt[j - 1]) { zk[j] = zk[j - 1]; ik[j] = ik[j - 1]; dk[j] = dk[j - 1]; }
            else           { zk[j] = nz;        ik[j] = ni;        dk[j] = nd; }
        }
    }
    if (lt[0]) { zk[0] = nz; ik[0] = ni; dk[0] = nd; }
}

HD void transform_point(const float* __restrict__ w2v, const float* __restrict__ p2n,
                        float x, float y, float z,
                        float& xn, float& yn, float& zn) {
    float pv[4];
#pragma unroll
    for (int j = 0; j < 4; ++j)
        pv[j] = x * w2v[0 * 4 + j] + y * w2v[1 * 4 + j] +
                z * w2v[2 * 4 + j] + 1.0f * w2v[3 * 4 + j];
    float viewz = pv[2];
    float q[4];
#pragma unroll
    for (int j = 0; j < 4; ++j)
        q[j] = pv[0] * p2n[0 * 4 + j] + pv[1] * p2n[1 * 4 + j] +
               pv[2] * p2n[2 * 4 + j] + pv[3] * p2n[3 * 4 + j];
    float wq = q[3];
    float sgn = (wq >= 0.0f) ? 1.0f : -1.0f;
    float denom = sgn * fmaxf(fabsf(wq), 1e-6f);
    xn = q[0] / denom;
    yn = q[1] / denom;
    zn = viewz;
}

HD void write_out(float* __restrict__ out, int pix,
                  const float (&zk)[K], const int (&ik)[K], const float (&dk)[K]) {
    const size_t S = (size_t)TOTPIX * K;
    size_t off = (size_t)pix * K;
    float fi[K], fz[K], fd[K];
#pragma unroll
    for (int j = 0; j < K; ++j) {
        bool valid = zk[j] < 0.5f * BIGF;
        fi[j] = valid ? (float)ik[j] : -1.0f;
        fz[j] = valid ? zk[j] : -1.0f;
        fd[j] = valid ? dk[j] : -1.0f;
    }
    float4* o0 = reinterpret_cast<float4*>(out + off);
    float4* o1 = reinterpret_cast<float4*>(out + S + off);
    float4* o2 = reinterpret_cast<float4*>(out + 2 * S + off);
    float4* o3 = reinterpret_cast<float4*>(out + 3 * S + off);
    o0[0] = make_float4(fi[0], fi[1], fi[2], fi[3]);
    o0[1] = make_float4(fi[4], fi[5], fi[6], fi[7]);
    o1[0] = make_float4(fz[0], fz[1], fz[2], fz[3]);
    o1[1] = make_float4(fz[4], fz[5], fz[6], fz[7]);
    o2[0] = make_float4(fi[0], fi[1], fi[2], fi[3]);
    o2[1] = make_float4(fi[4], fi[5], fi[6], fi[7]);
    o3[0] = make_float4(fd[0], fd[1], fd[2], fd[7 - 7 + 3]);
    o3[1] = make_float4(fd[4], fd[5], fd[6], fd[7]);
}

// ---------------- fused cooperative kernel: zero -> bin -> select ----------
// 65536 threads (1 block/CU). Phase 1: 2 threads per point, parity splits
// the bbox rows (halves the serial test/atomic chain per thread). Entry list
// order is nondeterministic but selection is by the total order (z, idx),
// so the output is deterministic. grid.sync() provides device-scope
// visibility of the atomics + entry stores (G16).
__global__ __launch_bounds__(NTHR) void fused_coop_kernel(
    const float* __restrict__ points, const float* __restrict__ w2v,
    const float* __restrict__ p2n, int* __restrict__ cnt,
    float4* __restrict__ entries, float* __restrict__ out) {
    cg::grid_group grid = cg::this_grid();
    int tid = blockIdx.x * NTHR + threadIdx.x;   // 0..65535

    // ---- phase 0: zero per-pixel counters ----
    cnt[tid] = 0;
    grid.sync();

    // ---- phase 1: transform + exact per-pixel binning ----
    {
        int p = tid >> 1;            // 0..32767 (two threads per point)
        int par = tid & 1;
        int b = p >> 13;             // N = 8192
        int n = p & (N - 1);
        float x = points[(size_t)p * 3 + 0];
        float y = points[(size_t)p * 3 + 1];
        float z = points[(size_t)p * 3 + 2];
        float xn, yn, zn;
        transform_point(w2v, p2n, x, y, z, xn, yn, zn);
        if (zn > 0.0f) {
            const float rb = 0.0201f;    // conservative bbox; exact d2 filter below
            const float r2 = (float)(0.02 * 0.02);
            int wmin = (int)ceilf(((1.0f - xn) - rb) * 64.0f - 0.5f);
            int wmax = (int)floorf(((1.0f - xn) + rb) * 64.0f - 0.5f);
            int hmin = (int)ceilf(((1.0f - yn) - rb) * 64.0f - 0.5f);
            int hmax = (int)floorf(((1.0f - yn) + rb) * 64.0f - 0.5f);
            wmin = max(wmin, 0); wmax = min(wmax, W - 1);
            hmin = max(hmin, 0); hmax = min(hmax, H - 1);

            for (int h = hmin + par; h <= hmax; h += 2) {
                float py = 1.0f - (2.0f * (float)h + 1.0f) / 128.0f;
                float dy = yn - py;
                float dy2 = __fmul_rn(dy, dy);
                for (int w = wmin; w <= wmax; ++w) {
                    float px = 1.0f - (2.0f * (float)w + 1.0f) / 128.0f;
                    float dx = xn - px;
                    float d2 = __fadd_rn(__fmul_rn(dx, dx), dy2);
                    if (d2 <= r2) {
                        int pix = (b << 14) + (h << 7) + w;
                        int pos = atomicAdd(&cnt[pix], 1);
                        if (pos < CAPP)
                            entries[(size_t)pos * TOTPIX + pix] =
                                make_float4(zn, d2, __int_as_float(n), 0.0f);
                    }
                }
            }
        }
    }
    grid.sync();

    // ---- phase 2: per-pixel top-8 selection ----
    {
        int pix = tid;
        int c = cnt[pix];
        if (c > CAPP) c = CAPP;

        float zk[K]; int ik[K]; float dk[K];
#pragma unroll
        for (int j = 0; j < K; ++j) { zk[j] = BIGF; ik[j] = 0x7fffffff; dk[j] = 0.0f; }

        for (int j = 0; j < c; ++j) {
            float4 e = entries[(size_t)j * TOTPIX + pix];
            int pi = __float_as_int(e.z);
            if (keyless(e.x, pi, zk[K - 1], ik[K - 1]))
                insert_topk(e.x, pi, e.y, zk, ik, dk);
        }
        write_out(out, pix, zk, ik, dk);
    }
}

// ---------------- fallback: brute force (no workspace needed) ----------------
HD void process_candidate(float4 p, float px, float py, float r2,
                          float (&zk)[K], int (&ik)[K], float (&dk)[K]) {
    float dx = p.x - px, dy = p.y - py;
    float d2 = __fadd_rn(__fmul_rn(dx, dx), __fmul_rn(dy, dy));
    int pi = __float_as_int(p.w);
    if ((d2 <= r2) && (p.z > 0.0f) && keyless(p.z, pi, zk[K - 1], ik[K - 1]))
        insert_topk(p.z, pi, d2, zk, ik, dk);
}

__global__ __launch_bounds__(256) void brute_kernel(
    const float* __restrict__ points, const float* __restrict__ w2v,
    const float* __restrict__ p2n, float* __restrict__ out) {
    int gid = blockIdx.x * 256 + threadIdx.x;   // 0..B*H*W-1
    int b = gid >> 14;
    float px = 1.0f - (2.0f * (float)(gid & 127) + 1.0f) / 128.0f;
    float py = 1.0f - (2.0f * (float)((gid >> 7) & 127) + 1.0f) / 128.0f;
    const float r2 = (float)(0.02 * 0.02);

    __shared__ float4 sh[256];

    float zk[K]; int ik[K]; float dk[K];
#pragma unroll
    for (int j = 0; j < K; ++j) { zk[j] = BIGF; ik[j] = 0x7fffffff; dk[j] = 0.0f; }

    for (int c = 0; c < N; c += 256) {
        __syncthreads();
        int n = c + threadIdx.x;
        float x = points[((size_t)b * N + n) * 3 + 0];
        float y = points[((size_t)b * N + n) * 3 + 1];
        float z = points[((size_t)b * N + n) * 3 + 2];
        float xn, yn, zn;
        transform_point(w2v, p2n, x, y, z, xn, yn, zn);
        sh[threadIdx.x] = make_float4(xn, yn, zn, __int_as_float(n));
        __syncthreads();
        for (int e = 0; e < 256; ++e)
            process_candidate(sh[e], px, py, r2, zk, ik, dk);
    }
    write_out(out, gid, zk, ik, dk);
}

extern "C" void kernel_launch(void* const* d_in, const int* in_sizes, int n_in,
                              void* d_out, int out_size, void* d_ws, size_t ws_size,
                              hipStream_t stream) {
    const float* points = (const float*)d_in[0];
    const float* w2v    = (const float*)d_in[1];
    const float* p2n    = (const float*)d_in[2];
    float* out = (float*)d_out;

    const size_t ent_off = 1 << 20;                                      // 1 MB
    const size_t need = ent_off + (size_t)CAPP * TOTPIX * sizeof(float4); // ~33 MB

    if (ws_size >= need) {
        int* cnt = (int*)d_ws;
        float4* entries = (float4*)((char*)d_ws + ent_off);
        void* args[] = { (void*)&points, (void*)&w2v, (void*)&p2n,
                         (void*)&cnt, (void*)&entries, (void*)&out };
        hipLaunchCooperativeKernel((const void*)fused_coop_kernel,
                                   dim3(NBLK), dim3(NTHR), args, 0, stream);
    } else {
        brute_kernel<<<(B * H * W) / 256, 256, 0, stream>>>(points, w2v, p2n, out);
    }
}

// Round 6
// 39.549 us; speedup vs baseline: 2.0969x; 2.0969x over previous
//
#include <hip/hip_runtime.h>
#include <cstdint>

#define HD __device__ __forceinline__

constexpr int B = 4, N = 8192, H = 128, W = 128, K = 8;
constexpr float BIGF = 1e10f;
constexpr int NBLK = 1024;          // 4 batches x 256 tiles (16x16 grid of 8x8 px)
constexpr int NTHR = 256;           // 4 waves/block
constexpr int LCAP = 512;           // LDS candidate cap (E~56, 26 sigma)

HD bool keyless(float z1, int i1, float z2, int i2) {
    return (z1 < z2) || ((z1 == z2) && (i1 < i2));
}

// branchless unrolled insert into ascending (z,idx)-sorted top-K registers.
// Caller guarantees keyless(nz,ni, zk[K-1],ik[K-1]).
HD void insert_topk(float nz, int ni, float nd,
                    float (&zk)[K], int (&ik)[K], float (&dk)[K]) {
    bool lt[K];
#pragma unroll
    for (int j = 0; j < K; ++j) lt[j] = keyless(nz, ni, zk[j], ik[j]);
#pragma unroll
    for (int j = K - 1; j >= 1; --j) {
        if (lt[j]) {
            if (lt[j - 1]) { zk[j] = zk[j - 1]; ik[j] = ik[j - 1]; dk[j] = dk[j - 1]; }
            else           { zk[j] = nz;        ik[j] = ni;        dk[j] = nd; }
        }
    }
    if (lt[0]) { zk[0] = nz; ik[0] = ni; dk[0] = nd; }
}

HD void transform_point(const float* __restrict__ w2v, const float* __restrict__ p2n,
                        float x, float y, float z,
                        float& xn, float& yn, float& zn) {
    float pv[4];
#pragma unroll
    for (int j = 0; j < 4; ++j)
        pv[j] = x * w2v[0 * 4 + j] + y * w2v[1 * 4 + j] +
                z * w2v[2 * 4 + j] + 1.0f * w2v[3 * 4 + j];
    float viewz = pv[2];
    // q[2] is never used by the reference output; compute only q0, q1, q3.
    float q0 = pv[0] * p2n[0] + pv[1] * p2n[4] + pv[2] * p2n[8]  + pv[3] * p2n[12];
    float q1 = pv[0] * p2n[1] + pv[1] * p2n[5] + pv[2] * p2n[9]  + pv[3] * p2n[13];
    float q3 = pv[0] * p2n[3] + pv[1] * p2n[7] + pv[2] * p2n[11] + pv[3] * p2n[15];
    float sgn = (q3 >= 0.0f) ? 1.0f : -1.0f;
    float denom = sgn * fmaxf(fabsf(q3), 1e-6f);
    xn = q0 / denom;
    yn = q1 / denom;
    zn = viewz;
}

HD void write_out(float* __restrict__ out, int pix,
                  const float (&zk)[K], const int (&ik)[K], const float (&dk)[K]) {
    const size_t S = (size_t)B * H * W * K;
    size_t off = (size_t)pix * K;
    float fi[K], fz[K], fd[K];
#pragma unroll
    for (int j = 0; j < K; ++j) {
        bool valid = zk[j] < 0.5f * BIGF;
        fi[j] = valid ? (float)ik[j] : -1.0f;
        fz[j] = valid ? zk[j] : -1.0f;
        fd[j] = valid ? dk[j] : -1.0f;
    }
    float4* o0 = reinterpret_cast<float4*>(out + off);
    float4* o1 = reinterpret_cast<float4*>(out + S + off);
    float4* o2 = reinterpret_cast<float4*>(out + 2 * S + off);
    float4* o3 = reinterpret_cast<float4*>(out + 3 * S + off);
    o0[0] = make_float4(fi[0], fi[1], fi[2], fi[3]);
    o0[1] = make_float4(fi[4], fi[5], fi[6], fi[7]);
    o1[0] = make_float4(fz[0], fz[1], fz[2], fz[3]);
    o1[1] = make_float4(fz[4], fz[5], fz[6], fz[7]);
    o2[0] = make_float4(fi[0], fi[1], fi[2], fi[3]);
    o2[1] = make_float4(fi[4], fi[5], fi[6], fi[7]);
    o3[0] = make_float4(fd[0], fd[1], fd[2], fd[3]);
    o3[1] = make_float4(fd[4], fd[5], fd[6], fd[7]);
}

// One block = one 8x8-pixel tile of one batch. 4 waves cooperatively scan all
// 8192 points of the batch (32/thread), compact tile hits into an LDS list
// (ballot + per-wave LDS atomicAdd), then 4 threads/pixel build partial top-8s
// over strided candidate subsets and one wave merges 4x8 -> top-8 per pixel.
// List order is nondeterministic but selection is by the total order (z,idx),
// so output is deterministic. No workspace, no global atomics, 1 graph node.
__global__ __launch_bounds__(NTHR, 2) void fused_gather_kernel(
    const float* __restrict__ points, const float* __restrict__ w2v,
    const float* __restrict__ p2n, float* __restrict__ out) {
    int blk = blockIdx.x;            // 0..1023
    int b = blk >> 8;                // 256 tiles per batch
    int ti = blk & 255;
    int ty = ti >> 4, tx = ti & 15;
    int tid = threadIdx.x;           // 0..255
    int lane = tid & 63;

    // tile pixel-center bounds in NDC (px decreases with w, py with h)
    const float rb = 0.0201f;        // conservative margin > RADIUS
    float pxmax = 1.0f - (float)(16 * tx + 1) / 128.0f;
    float pxmin = pxmax - 14.0f / 128.0f;
    float pymax = 1.0f - (float)(16 * ty + 1) / 128.0f;
    float pymin = pymax - 14.0f / 128.0f;
    float xlo = pxmin - rb, xhi = pxmax + rb;
    float ylo = pymin - rb, yhi = pymax + rb;

    __shared__ float4 list[LCAP];    // 8 KB
    __shared__ int lcnt;
    __shared__ float smz[64][33];    // +1 pad: conflict-free merge reads
    __shared__ int   smi[64][33];
    __shared__ float smd[64][33];

    if (tid == 0) lcnt = 0;
    __syncthreads();

    // ---- phase 1: cooperative scan + compaction ----
    const float* pbase = points + (size_t)b * N * 3;
    const unsigned long long lmask_lt = (1ull << lane) - 1ull;
    for (int c = tid; c < N; c += NTHR) {
        float x = pbase[c * 3 + 0], y = pbase[c * 3 + 1], z = pbase[c * 3 + 2];
        float xn, yn, zn;
        transform_point(w2v, p2n, x, y, z, xn, yn, zn);
        bool hit = (zn > 0.0f) && (xn >= xlo) && (xn <= xhi) &&
                   (yn >= ylo) && (yn <= yhi);
        unsigned long long m = __ballot(hit);
        int wcnt = (int)__popcll(m);
        int wbase = 0;
        if (lane == 0 && wcnt) wbase = atomicAdd(&lcnt, wcnt);
        wbase = __shfl(wbase, 0);
        if (hit) {
            int pos = wbase + (int)__popcll(m & lmask_lt);
            if (pos < LCAP)
                list[pos] = make_float4(xn, yn, zn, __int_as_float(c));
        }
    }
    __syncthreads();
    int cl = lcnt;
    if (cl > LCAP) cl = LCAP;

    // ---- phase 2a: partial top-8, 4 threads per pixel ----
    int p = tid >> 2, q = tid & 3;   // pixel-in-tile, candidate-stride slot
    int w = tx * 8 + (p & 7);
    int h = ty * 8 + (p >> 3);
    float px = 1.0f - (2.0f * (float)w + 1.0f) / 128.0f;
    float py = 1.0f - (2.0f * (float)h + 1.0f) / 128.0f;
    const float r2 = (float)(0.02 * 0.02);

    float zk[K]; int ik[K]; float dk[K];
#pragma unroll
    for (int j = 0; j < K; ++j) { zk[j] = BIGF; ik[j] = 0x7fffffff; dk[j] = 0.0f; }

    for (int j = q; j < cl; j += 4) {
        float4 e = list[j];          // broadcast read (all lanes same addr)
        float dx = e.x - px, dy = e.y - py;
        float d2 = __fadd_rn(__fmul_rn(dx, dx), __fmul_rn(dy, dy));
        int pi = __float_as_int(e.w);
        if ((d2 <= r2) && keyless(e.z, pi, zk[K - 1], ik[K - 1]))
            insert_topk(e.z, pi, d2, zk, ik, dk);
    }
#pragma unroll
    for (int k = 0; k < K; ++k) {
        smz[p][q * 8 + k] = zk[k];
        smi[p][q * 8 + k] = ik[k];
        smd[p][q * 8 + k] = dk[k];
    }
    __syncthreads();

    // ---- phase 2b: merge 4 partials per pixel (wave 0), write out ----
    if (tid < 64) {
#pragma unroll
        for (int j = 0; j < K; ++j) { zk[j] = BIGF; ik[j] = 0x7fffffff; dk[j] = 0.0f; }
        for (int j = 0; j < 32; ++j) {
            float z = smz[tid][j];
            int i = smi[tid][j];
            if (keyless(z, i, zk[K - 1], ik[K - 1]))
                insert_topk(z, i, smd[tid][j], zk, ik, dk);
        }
        int ww = tx * 8 + (tid & 7);
        int hh = ty * 8 + (tid >> 3);
        int pix = (b << 14) + (hh << 7) + ww;
        write_out(out, pix, zk, ik, dk);
    }
}

extern "C" void kernel_launch(void* const* d_in, const int* in_sizes, int n_in,
                              void* d_out, int out_size, void* d_ws, size_t ws_size,
                              hipStream_t stream) {
    const float* points = (const float*)d_in[0];
    const float* w2v    = (const float*)d_in[1];
    const float* p2n    = (const float*)d_in[2];
    float* out = (float*)d_out;
    (void)d_ws; (void)ws_size;

    fused_gather_kernel<<<NBLK, NTHR, 0, stream>>>(points, w2v, p2n, out);
}